// Round 1
// baseline (3435.515 us; speedup 1.0000x reference)
//
#include <hip/hip_runtime.h>

// Problem constants (from reference): B=4, C=64, H=384, W=768
#define Bc  4
#define Cc  64
#define Hc  384
#define Wc  768
#define HWc (Hc * Wc)            // 294912
#define FEATc ((long)Bc * Cc * HWc)  // 75497472

// ---------------------------------------------------------------------------
// K1: scatter splat. One thread per (b, source pixel).
//   idx = floor(y+flow_y)*W + floor(x+flow_x)   (single-bin splat, no bilinear)
//   w   = exp(-depth)
//   wacc[b, idx]   += w            (wacc lives in d_out's mask region)
//   facc[b, c, idx] += fmap[b,c,p] * w   for all 64 channels
// Loads of fmap are coalesced across lanes (fixed c, consecutive p).
// ---------------------------------------------------------------------------
__global__ __launch_bounds__(256) void scatter_k(
    const float* __restrict__ fmap,
    const float* __restrict__ flow,
    const float* __restrict__ depth,
    float* __restrict__ facc,
    float* __restrict__ wacc)
{
    const int p = blockIdx.x * 256 + threadIdx.x;   // 0..HW-1 (HW % 256 == 0)
    const int b = blockIdx.y;

    const float fx = flow[((long)b * 2 + 0) * HWc + p];
    const float fy = flow[((long)b * 2 + 1) * HWc + p];
    const int x = p % Wc;
    const int y = p / Wc;
    const float tx = (float)x + fx;
    const float ty = (float)y + fy;

    // valid: tx in [0, W-1), ty in [0, H-1)  (strict upper bound, like reference)
    if (!(tx >= 0.f && tx < (float)(Wc - 1) && ty >= 0.f && ty < (float)(Hc - 1)))
        return;

    const int idx = (int)ty * Wc + (int)tx;   // trunc == floor for tx,ty >= 0
    const float w = __expf(-depth[(long)b * HWc + p]);

    atomicAdd(wacc + (long)b * HWc + idx, w);

    const float* src = fmap + (long)b * Cc * HWc + p;
    float*       dst = facc + (long)b * Cc * HWc + idx;
#pragma unroll
    for (int c = 0; c < Cc; ++c) {
        atomicAdd(dst + (long)c * HWc, src[(long)c * HWc] * w);
    }
}

// ---------------------------------------------------------------------------
// K2: normalize features in place: facc /= w where w > 0 (else stays 0).
// float4-vectorized; all index math 32-bit.
// Blocks per batch = C*HW / (4*256) = 18432.
// ---------------------------------------------------------------------------
__global__ __launch_bounds__(256) void norm_k(
    float* __restrict__ facc,
    const float* __restrict__ wacc)
{
    const int bpb = (Cc * HWc) / 1024;          // 18432 blocks per batch
    const int b   = blockIdx.x / bpb;
    const int blk = blockIdx.x % bpb;
    const int e   = blk * 1024 + threadIdx.x * 4;   // element within batch, < C*HW
    const int p   = e % HWc;

    const float4 w4 = *(const float4*)(wacc + (long)b * HWc + p);
    float4 f = *(float4*)(facc + (long)b * (Cc * HWc) + e);
    if (w4.x > 0.f) f.x /= w4.x;
    if (w4.y > 0.f) f.y /= w4.y;
    if (w4.z > 0.f) f.z /= w4.z;
    if (w4.w > 0.f) f.w /= w4.w;
    *(float4*)(facc + (long)b * (Cc * HWc) + e) = f;
}

// ---------------------------------------------------------------------------
// K3: convert accumulated weights to the 0/1 mask, in place.
// Runs after K2 so the weights are still intact during normalization.
// ---------------------------------------------------------------------------
__global__ __launch_bounds__(256) void mask_k(float* __restrict__ wacc)
{
    const int i = blockIdx.x * 256 + threadIdx.x;   // float4 index, B*HW/4 total
    float4 w = *(float4*)(wacc + (long)i * 4);
    w.x = (w.x > 0.f) ? 1.f : 0.f;
    w.y = (w.y > 0.f) ? 1.f : 0.f;
    w.z = (w.z > 0.f) ? 1.f : 0.f;
    w.w = (w.w > 0.f) ? 1.f : 0.f;
    *(float4*)(wacc + (long)i * 4) = w;
}

extern "C" void kernel_launch(void* const* d_in, const int* in_sizes, int n_in,
                              void* d_out, int out_size, void* d_ws, size_t ws_size,
                              hipStream_t stream)
{
    const float* fmap  = (const float*)d_in[0];   // (B,C,H,W)
    const float* flow  = (const float*)d_in[1];   // (B,2,H,W)
    const float* depth = (const float*)d_in[2];   // (B,1,H,W)

    float* out  = (float*)d_out;
    float* facc = out;            // final features: B*C*HW floats
    float* wacc = out + FEATc;    // weight accumulator -> becomes mask: B*HW floats

    // Zero the whole output buffer (accumulators need zero-init; harness poisons).
    hipMemsetAsync(d_out, 0, (size_t)out_size * sizeof(float), stream);

    dim3 g1(HWc / 256, Bc);
    scatter_k<<<g1, 256, 0, stream>>>(fmap, flow, depth, facc, wacc);

    const int norm_blocks = (int)(FEATc / 1024);      // 73728
    norm_k<<<norm_blocks, 256, 0, stream>>>(facc, wacc);

    const int mask_blocks = (Bc * HWc) / 1024;        // 1152
    mask_k<<<mask_blocks, 256, 0, stream>>>(wacc);
}